// Round 7
// baseline (1493.802 us; speedup 1.0000x reference)
//
#include <hip/hip_runtime.h>
#include <math.h>

// GATTransformerLayer: GATConv(+self-loops, segment softmax) -> +x, LN1 -> FFN(relu) -> +v, LN2
// N=50000, E=800000, D=128, FF=512, H=1.
// Established: inputs f32, output f32, edge_index int32 on device (probe kept for safety).
// R7 fix: k_ffn LN2 epilogue covered only rows 0-15 of each 32-row tile (4 waves x 4 rows);
// now 4 waves x 8 rows = all 32. This single bug explains R0/R5's 4.84 (skipped rows = 0)
// and R6's 2.16 (skipped rows = aliased post-LN1 v1) exactly.

#define LN_EPS 1e-5f
#define NEG_SLOPE 0.2f

// monotone f32 <-> uint key for atomicMax over floats (incl. negatives)
__device__ __forceinline__ unsigned fkey(float f) {
    unsigned b = __float_as_uint(f);
    return (b & 0x80000000u) ? ~b : (b | 0x80000000u);
}
__device__ __forceinline__ float fdec(unsigned k) {
    return (k & 0x80000000u) ? __uint_as_float(k & 0x7FFFFFFFu) : __uint_as_float(~k);
}

__device__ __forceinline__ void edge_sd(const int* __restrict__ ei, int flag, int i,
                                        int e, int n, int& s, int& d) {
    if (i < e) {
        s = ei[flag ? (i << 1) : i];
        d = ei[flag ? ((e + i) << 1) : (e + i)];
    } else {
        s = d = i - e;  // appended self loop
    }
}

// ---------------- K0: edge_index layout probe (int32 vs int64) ----------------
__global__ __launch_bounds__(256) void k_detect(const int* __restrict__ ei,
                                                int* __restrict__ flag) {
    __shared__ int s;
    if (threadIdx.x == 0) s = 0;
    __syncthreads();
    int acc = 0;
    for (int i = threadIdx.x; i < 4096; i += 256) acc |= ei[2 * i + 1];
    if (acc) atomicOr(&s, 1);
    __syncthreads();
    if (threadIdx.x == 0) *flag = (s == 0) ? 1 : 0;
}

// ---------------- K1: h = x @ W  (N x 128)(128 x 128) ----------------
__global__ __launch_bounds__(256) void k_gemm_h(const float* __restrict__ x,
                                                const float* __restrict__ W,
                                                float* __restrict__ h) {
    __shared__ float xs[8][128];
    int t = threadIdx.x;
    int rowBase = blockIdx.x * 8;
    const float4* x4 = reinterpret_cast<const float4*>(x + (size_t)rowBase * 128);
    reinterpret_cast<float4*>(&xs[0][0])[t] = x4[t];
    __syncthreads();
    int c = t & 127;
    int g = t >> 7;
    float a0 = 0.f, a1 = 0.f, a2 = 0.f, a3 = 0.f;
    #pragma unroll 4
    for (int k = 0; k < 128; ++k) {
        float w = W[k * 128 + c];
        a0 += xs[g * 4 + 0][k] * w;
        a1 += xs[g * 4 + 1][k] * w;
        a2 += xs[g * 4 + 2][k] * w;
        a3 += xs[g * 4 + 3][k] * w;
    }
    size_t r = (size_t)(rowBase + g * 4) * 128 + c;
    h[r + 0 * 128] = a0;
    h[r + 1 * 128] = a1;
    h[r + 2 * 128] = a2;
    h[r + 3 * 128] = a3;
}

// ---------------- K1b: attention scores ----------------
__global__ __launch_bounds__(256) void k_scores(const float* __restrict__ h,
                                                const float* __restrict__ att_src,
                                                const float* __restrict__ att_dst,
                                                float* __restrict__ a_src,
                                                float* __restrict__ a_dst, int n) {
    int wid = (blockIdx.x * 256 + threadIdx.x) >> 6;
    int lane = threadIdx.x & 63;
    if (wid >= n) return;
    float2 hv = reinterpret_cast<const float2*>(h + (size_t)wid * 128)[lane];
    float2 as = reinterpret_cast<const float2*>(att_src)[lane];
    float2 ad = reinterpret_cast<const float2*>(att_dst)[lane];
    float ps = hv.x * as.x + hv.y * as.y;
    float pd = hv.x * ad.x + hv.y * ad.y;
    for (int off = 32; off; off >>= 1) {
        ps += __shfl_xor(ps, off);
        pd += __shfl_xor(pd, off);
    }
    if (lane == 0) { a_src[wid] = ps; a_dst[wid] = pd; }
}

// ---------------- init amax keys / denominators ----------------
__global__ void k_init_md(unsigned* __restrict__ amax_key, float* __restrict__ den, int n) {
    int i = blockIdx.x * 256 + threadIdx.x;
    if (i < n) { amax_key[i] = 0u; den[i] = 0.f; }
}

// ---------------- zero the accumulator (aliases d_out) ----------------
__global__ void k_zero(float4* __restrict__ p, int n4) {
    for (int i = blockIdx.x * 256 + threadIdx.x; i < n4; i += gridDim.x * 256)
        p[i] = make_float4(0.f, 0.f, 0.f, 0.f);
}

// ---------------- edge pass 1: segment max ----------------
__global__ void k_edge_max(const int* __restrict__ ei, const int* __restrict__ flagp,
                           const float* __restrict__ a_src, const float* __restrict__ a_dst,
                           unsigned* __restrict__ amax_key, int e, int n) {
    int i = blockIdx.x * 256 + threadIdx.x;
    if (i >= e + n) return;
    int flag = *flagp, s, d;
    edge_sd(ei, flag, i, e, n, s, d);
    float a = a_src[s] + a_dst[d];
    a = (a >= 0.f) ? a : NEG_SLOPE * a;
    atomicMax(&amax_key[d], fkey(a));
}

// ---------------- edge pass 2: denominator ----------------
__global__ void k_edge_den(const int* __restrict__ ei, const int* __restrict__ flagp,
                           const float* __restrict__ a_src, const float* __restrict__ a_dst,
                           const unsigned* __restrict__ amax_key, float* __restrict__ den,
                           int e, int n) {
    int i = blockIdx.x * 256 + threadIdx.x;
    if (i >= e + n) return;
    int flag = *flagp, s, d;
    edge_sd(ei, flag, i, e, n, s, d);
    float a = a_src[s] + a_dst[d];
    a = (a >= 0.f) ? a : NEG_SLOPE * a;
    atomicAdd(&den[d], expf(a - fdec(amax_key[d])));
}

// ---------------- edge pass 3: weighted scatter (wave per edge, 2 ch/lane) ----------------
__global__ __launch_bounds__(256) void k_edge_acc(const int* __restrict__ ei,
                                                  const int* __restrict__ flagp,
                                                  const float* __restrict__ a_src,
                                                  const float* __restrict__ a_dst,
                                                  const unsigned* __restrict__ amax_key,
                                                  const float* __restrict__ den,
                                                  const float* __restrict__ h,
                                                  float* __restrict__ acc, int e, int n) {
    int i = (int)(((long long)blockIdx.x * 256 + threadIdx.x) >> 6);
    int lane = threadIdx.x & 63;
    if (i >= e + n) return;
    int flag = *flagp, s, d;
    edge_sd(ei, flag, i, e, n, s, d);
    float a = a_src[s] + a_dst[d];
    a = (a >= 0.f) ? a : NEG_SLOPE * a;
    float w = expf(a - fdec(amax_key[d])) / (den[d] + 1e-16f);
    float2 hv = reinterpret_cast<const float2*>(h + (size_t)s * 128)[lane];
    atomicAdd(&acc[(size_t)d * 128 + 2 * lane + 0], w * hv.x);
    atomicAdd(&acc[(size_t)d * 128 + 2 * lane + 1], w * hv.y);
}

// ---------------- K5: +bias +residual, LN1 (in place on v = acc = d_out) ----------------
__global__ __launch_bounds__(256) void k_post(float* v,  // no restrict: in-place
                                              const float* __restrict__ x,
                                              const float* __restrict__ gat_bias,
                                              const float* __restrict__ ln1_g,
                                              const float* __restrict__ ln1_b, int n) {
    int wid = (blockIdx.x * 256 + threadIdx.x) >> 6;
    int lane = threadIdx.x & 63;
    if (wid >= n) return;
    float2 av = reinterpret_cast<const float2*>(v + (size_t)wid * 128)[lane];
    float2 gb = reinterpret_cast<const float2*>(gat_bias)[lane];
    float2 xr = reinterpret_cast<const float2*>(x + (size_t)wid * 128)[lane];
    float ox = av.x + gb.x + xr.x;
    float oy = av.y + gb.y + xr.y;
    float sum = ox + oy;
    for (int off = 32; off; off >>= 1) sum += __shfl_xor(sum, off);
    float m = sum * (1.f / 128.f);
    float dx = ox - m, dy = oy - m;
    float sq = dx * dx + dy * dy;
    for (int off = 32; off; off >>= 1) sq += __shfl_xor(sq, off);
    float rstd = rsqrtf(sq * (1.f / 128.f) + LN_EPS);
    float2 g = reinterpret_cast<const float2*>(ln1_g)[lane];
    float2 b = reinterpret_cast<const float2*>(ln1_b)[lane];
    float2 o;
    o.x = dx * rstd * g.x + b.x;
    o.y = dy * rstd * g.y + b.y;
    reinterpret_cast<float2*>(v + (size_t)wid * 128)[lane] = o;
}

// ---------------- K6: fused FFN + residual + LN2, in place (vout = v1 = out) ----------------
__global__ __launch_bounds__(256) void k_ffn(float* vout,  // no restrict: aliased v1/out
                                             const float* __restrict__ W1,
                                             const float* __restrict__ b1,
                                             const float* __restrict__ W2,
                                             const float* __restrict__ b2,
                                             const float* __restrict__ ln2_g,
                                             const float* __restrict__ ln2_b, int n) {
    __shared__ float vt[32][128];  // v1 tile (residual, then LN input)
    __shared__ float tt[32][64];   // relu'd hidden chunk
    int t = threadIdx.x;
    int rowBase = blockIdx.x * 32;
    {   // stage v1 tile BEFORE any write to these rows (makes in-place safe)
        const float4* src = reinterpret_cast<const float4*>(vout + (size_t)rowBase * 128);
        float4* dst = reinterpret_cast<float4*>(&vt[0][0]);
        #pragma unroll
        for (int k = 0; k < 4; ++k) {
            int idx = t + k * 256;
            int r = idx >> 5;
            float4 val = make_float4(0.f, 0.f, 0.f, 0.f);
            if (rowBase + r < n) val = src[idx];
            dst[idx] = val;
        }
    }
    __syncthreads();
    int cc = t & 127;
    int half = t >> 7;
    int f = t & 63;
    int q = t >> 6;
    float acc[16];
    #pragma unroll
    for (int i = 0; i < 16; ++i) acc[i] = 0.f;

    for (int ch = 0; ch < 8; ++ch) {
        int f0 = ch * 64;
        float ta[8];
        #pragma unroll
        for (int i = 0; i < 8; ++i) ta[i] = 0.f;
        for (int k = 0; k < 128; ++k) {
            float w = W1[k * 512 + f0 + f];
            #pragma unroll
            for (int i = 0; i < 8; ++i) ta[i] += vt[q * 8 + i][k] * w;
        }
        float bb = b1[f0 + f];
        __syncthreads();
        #pragma unroll
        for (int i = 0; i < 8; ++i) {
            float v = ta[i] + bb;
            tt[q * 8 + i][f] = v > 0.f ? v : 0.f;
        }
        __syncthreads();
        for (int ff = 0; ff < 64; ++ff) {
            float w2 = W2[(size_t)(f0 + ff) * 128 + cc];
            #pragma unroll
            for (int i = 0; i < 16; ++i) acc[i] += tt[half * 16 + i][ff] * w2;
        }
    }
    __syncthreads();
    float bc = b2[cc];
    #pragma unroll
    for (int i = 0; i < 16; ++i) {
        int r = half * 16 + i;
        vt[r][cc] = acc[i] + bc + vt[r][cc];
    }
    __syncthreads();
    // LN2: 4 waves (256 threads) x 8 rows each = all 32 rows.
    // (R0-R6 bug: wv*4+j covered only rows 0-15; rows 16-31 never stored.)
    int wv = t >> 6, lane = t & 63;
    float2 g = reinterpret_cast<const float2*>(ln2_g)[lane];
    float2 b = reinterpret_cast<const float2*>(ln2_b)[lane];
    for (int j = 0; j < 8; ++j) {
        int r = wv * 8 + j;
        int grow = rowBase + r;
        float2 val = reinterpret_cast<const float2*>(&vt[r][0])[lane];
        float sum = val.x + val.y;
        for (int off = 32; off; off >>= 1) sum += __shfl_xor(sum, off);
        float m = sum * (1.f / 128.f);
        float dx = val.x - m, dy = val.y - m;
        float sq = dx * dx + dy * dy;
        for (int off = 32; off; off >>= 1) sq += __shfl_xor(sq, off);
        float rstd = rsqrtf(sq * (1.f / 128.f) + LN_EPS);
        float2 o;
        o.x = dx * rstd * g.x + b.x;
        o.y = dy * rstd * g.y + b.y;
        if (grow < n) reinterpret_cast<float2*>(vout + (size_t)grow * 128)[lane] = o;
    }
}

// ---------------- host launch ----------------
extern "C" void kernel_launch(void* const* d_in, const int* in_sizes, int n_in,
                              void* d_out, int out_size, void* d_ws, size_t ws_size,
                              hipStream_t stream) {
    const float* x        = (const float*)d_in[0];
    const int*   ei       = (const int*)d_in[1];
    // d_in[2] edge_attr ignored (edge_dim=None in reference)
    const float* W        = (const float*)d_in[3];
    const float* att_src  = (const float*)d_in[4];
    const float* att_dst  = (const float*)d_in[5];
    const float* gat_bias = (const float*)d_in[6];
    const float* W1       = (const float*)d_in[7];
    const float* b1       = (const float*)d_in[8];
    const float* W2       = (const float*)d_in[9];
    const float* b2       = (const float*)d_in[10];
    const float* ln1_g    = (const float*)d_in[11];
    const float* ln1_b    = (const float*)d_in[12];
    const float* ln2_g    = (const float*)d_in[13];
    const float* ln2_b    = (const float*)d_in[14];
    float* out = (float*)d_out;

    const int n = in_sizes[0] / 128;   // 50000
    const int e = in_sizes[1] / 2;     // 800000

    // workspace (~27 MB): h + scalar tables only; GAT accumulator/v1 alias d_out
    char* ws = (char*)d_ws;
    size_t off = 0;
    auto alloc = [&](size_t bytes) -> void* {
        void* p = ws + off;
        off += (bytes + 255) & ~(size_t)255;
        return p;
    };
    float*    h        = (float*)alloc((size_t)n * 128 * 4);
    float*    a_src    = (float*)alloc((size_t)n * 4);
    float*    a_dst    = (float*)alloc((size_t)n * 4);
    unsigned* amax_key = (unsigned*)alloc((size_t)n * 4);
    float*    den      = (float*)alloc((size_t)n * 4);
    int*      eflag    = (int*)alloc(256);

    const int nb_n  = (n + 255) / 256;
    const int nb_en = (e + n + 255) / 256;
    const int nb_acc = (int)(((long long)(e + n) * 64 + 255) / 256);

    hipLaunchKernelGGL(k_detect, dim3(1), dim3(256), 0, stream, ei, eflag);
    hipLaunchKernelGGL(k_gemm_h, dim3(n / 8), dim3(256), 0, stream, x, W, h);
    hipLaunchKernelGGL(k_scores, dim3((n + 3) / 4), dim3(256), 0, stream,
                       h, att_src, att_dst, a_src, a_dst, n);
    hipLaunchKernelGGL(k_init_md, dim3(nb_n), dim3(256), 0, stream, amax_key, den, n);
    hipLaunchKernelGGL(k_edge_max, dim3(nb_en), dim3(256), 0, stream,
                       ei, eflag, a_src, a_dst, amax_key, e, n);
    hipLaunchKernelGGL(k_edge_den, dim3(nb_en), dim3(256), 0, stream,
                       ei, eflag, a_src, a_dst, amax_key, den, e, n);
    hipLaunchKernelGGL(k_zero, dim3(2048), dim3(256), 0, stream,
                       (float4*)out, n * 32);
    hipLaunchKernelGGL(k_edge_acc, dim3(nb_acc), dim3(256), 0, stream,
                       ei, eflag, a_src, a_dst, amax_key, den, h, out, e, n);
    hipLaunchKernelGGL(k_post, dim3((n + 3) / 4), dim3(256), 0, stream,
                       out, x, gat_bias, ln1_g, ln1_b, n);
    hipLaunchKernelGGL(k_ffn, dim3((n + 31) / 32), dim3(256), 0, stream,
                       out, W1, b1, W2, b2, ln2_g, ln2_b, n);
}

// Round 8
// 430.931 us; speedup vs baseline: 3.4665x; 3.4665x over previous
//
#include <hip/hip_runtime.h>
#include <math.h>

// GATTransformerLayer: GATConv(+self-loops, segment softmax) -> +x, LN1 -> FFN(relu) -> +v, LN2
// N=50000, E=800000, D=128, FF=512, H=1.
// R8: (1) CSR gather aggregation (no feature atomics; R5-validated machinery),
//     (2) FFN via bf16 MFMA 16x16x32 with pre-swizzled weight fragments, f32 accum.
// Inputs f32, output f32, edge_index int32 (runtime probe kept).

#define LN_EPS 1e-5f
#define NEG_SLOPE 0.2f

typedef unsigned short u16;
typedef __attribute__((ext_vector_type(8))) short bf16x8;
typedef __attribute__((ext_vector_type(4))) float f32x4;

__device__ __forceinline__ u16 f2bf(float f) {
    union { float f; unsigned i; } v;
    v.f = f;
    unsigned r = v.i + 0x7FFF + ((v.i >> 16) & 1);  // RNE
    return (u16)(r >> 16);
}

__device__ __forceinline__ void edge_sd(const int* __restrict__ ei, int flag, int i,
                                        int e, int n, int& s, int& d) {
    if (i < e) {
        s = ei[flag ? (i << 1) : i];
        d = ei[flag ? ((e + i) << 1) : (e + i)];
    } else {
        s = d = i - e;  // appended self loop
    }
}

// ---------------- K0: edge_index layout probe (int32 vs int64) ----------------
__global__ __launch_bounds__(256) void k_detect(const int* __restrict__ ei,
                                                int* __restrict__ flag) {
    __shared__ int s;
    if (threadIdx.x == 0) s = 0;
    __syncthreads();
    int acc = 0;
    for (int i = threadIdx.x; i < 4096; i += 256) acc |= ei[2 * i + 1];
    if (acc) atomicOr(&s, 1);
    __syncthreads();
    if (threadIdx.x == 0) *flag = (s == 0) ? 1 : 0;
}

// ---------------- K1: h = x @ W  (N x 128)(128 x 128) ----------------
__global__ __launch_bounds__(256) void k_gemm_h(const float* __restrict__ x,
                                                const float* __restrict__ W,
                                                float* __restrict__ h) {
    __shared__ float xs[8][128];
    int t = threadIdx.x;
    int rowBase = blockIdx.x * 8;
    const float4* x4 = reinterpret_cast<const float4*>(x + (size_t)rowBase * 128);
    reinterpret_cast<float4*>(&xs[0][0])[t] = x4[t];
    __syncthreads();
    int c = t & 127;
    int g = t >> 7;
    float a0 = 0.f, a1 = 0.f, a2 = 0.f, a3 = 0.f;
    #pragma unroll 4
    for (int k = 0; k < 128; ++k) {
        float w = W[k * 128 + c];
        a0 += xs[g * 4 + 0][k] * w;
        a1 += xs[g * 4 + 1][k] * w;
        a2 += xs[g * 4 + 2][k] * w;
        a3 += xs[g * 4 + 3][k] * w;
    }
    size_t r = (size_t)(rowBase + g * 4) * 128 + c;
    h[r + 0 * 128] = a0;
    h[r + 1 * 128] = a1;
    h[r + 2 * 128] = a2;
    h[r + 3 * 128] = a3;
}

// ---------------- K1b: attention scores ----------------
__global__ __launch_bounds__(256) void k_scores(const float* __restrict__ h,
                                                const float* __restrict__ att_src,
                                                const float* __restrict__ att_dst,
                                                float* __restrict__ a_src,
                                                float* __restrict__ a_dst, int n) {
    int wid = (blockIdx.x * 256 + threadIdx.x) >> 6;
    int lane = threadIdx.x & 63;
    if (wid >= n) return;
    float2 hv = reinterpret_cast<const float2*>(h + (size_t)wid * 128)[lane];
    float2 as = reinterpret_cast<const float2*>(att_src)[lane];
    float2 ad = reinterpret_cast<const float2*>(att_dst)[lane];
    float ps = hv.x * as.x + hv.y * as.y;
    float pd = hv.x * ad.x + hv.y * ad.y;
    for (int off = 32; off; off >>= 1) {
        ps += __shfl_xor(ps, off);
        pd += __shfl_xor(pd, off);
    }
    if (lane == 0) { a_src[wid] = ps; a_dst[wid] = pd; }
}

// ---------------- CSR build (R5-validated) ----------------
__global__ void k_init_deg(int* __restrict__ deg, int n) {
    int i = blockIdx.x * 256 + threadIdx.x;
    if (i < n) deg[i] = 1;  // self loop
}

__global__ void k_count(const int* __restrict__ ei, const int* __restrict__ flagp,
                        int* __restrict__ deg, int e) {
    int i = blockIdx.x * 256 + threadIdx.x;
    if (i >= e) return;
    int flag = *flagp;
    int d = ei[flag ? ((e + i) << 1) : (e + i)];
    atomicAdd(&deg[d], 1);
}

__global__ __launch_bounds__(256) void k_scan1(const int* __restrict__ deg,
                                               int* __restrict__ row_start,
                                               int* __restrict__ bsum, int n) {
    __shared__ int s[256];
    int t = threadIdx.x;
    int i = blockIdx.x * 256 + t;
    int v = (i < n) ? deg[i] : 0;
    s[t] = v;
    __syncthreads();
    for (int off = 1; off < 256; off <<= 1) {
        int a = (t >= off) ? s[t - off] : 0;
        __syncthreads();
        s[t] += a;
        __syncthreads();
    }
    if (i < n) row_start[i] = s[t] - v;  // exclusive within chunk
    if (t == 255) bsum[blockIdx.x] = s[255];
}

__global__ __launch_bounds__(256) void k_scan2(const int* __restrict__ bsum,
                                               int* __restrict__ carry, int nb) {
    __shared__ int s[256];
    int t = threadIdx.x;
    int v = (t < nb) ? bsum[t] : 0;
    s[t] = v;
    __syncthreads();
    for (int off = 1; off < 256; off <<= 1) {
        int a = (t >= off) ? s[t - off] : 0;
        __syncthreads();
        s[t] += a;
        __syncthreads();
    }
    carry[t] = s[t] - v;  // exclusive
}

__global__ void k_scan3(int* __restrict__ row_start, int* __restrict__ cursor,
                        const int* __restrict__ carry, int n, int total) {
    int i = blockIdx.x * 256 + threadIdx.x;
    if (i < n) {
        int v = row_start[i] + carry[i >> 8];
        row_start[i] = v;
        cursor[i] = v;
    }
    if (i == 0) row_start[n] = total;
}

__global__ void k_fill(const int* __restrict__ ei, const int* __restrict__ flagp,
                       const float* __restrict__ a_src, const float* __restrict__ a_dst,
                       int* __restrict__ cursor, int* __restrict__ srcs,
                       float* __restrict__ alph, int e, int n) {
    int i = blockIdx.x * 256 + threadIdx.x;
    if (i >= e + n) return;
    int flag = *flagp, s, d;
    edge_sd(ei, flag, i, e, n, s, d);
    float a = a_src[s] + a_dst[d];
    a = (a >= 0.f) ? a : NEG_SLOPE * a;
    int p = atomicAdd(&cursor[d], 1);
    srcs[p] = s;
    alph[p] = a;
}

// ---------------- K5: per-dst gather aggregate + bias + residual + LN1 -> out ----------------
__global__ __launch_bounds__(256) void k_aggregate(const float* __restrict__ h,
                                                   const int* __restrict__ row_start,
                                                   const int* __restrict__ srcs,
                                                   const float* __restrict__ alph,
                                                   const float* __restrict__ x,
                                                   const float* __restrict__ gat_bias,
                                                   const float* __restrict__ ln1_g,
                                                   const float* __restrict__ ln1_b,
                                                   float* __restrict__ v1, int n) {
    int wid = (blockIdx.x * 256 + threadIdx.x) >> 6;
    int lane = threadIdx.x & 63;
    if (wid >= n) return;
    int r0 = row_start[wid], r1 = row_start[wid + 1];
    // pass 1: segment max
    float mx = -3.4e38f;
    for (int e = r0 + lane; e < r1; e += 64) mx = fmaxf(mx, alph[e]);
    for (int off = 32; off; off >>= 1) mx = fmaxf(mx, __shfl_xor(mx, off));
    // pass 2: unnormalized weighted sum (softmax normalization is linear)
    float accx = 0.f, accy = 0.f, den = 0.f;
    for (int e = r0; e < r1; ++e) {
        float ex = expf(alph[e] - mx);
        den += ex;
        int s = srcs[e];
        float2 hv = reinterpret_cast<const float2*>(h + (size_t)s * 128)[lane];
        accx += ex * hv.x;
        accy += ex * hv.y;
    }
    float inv = 1.f / (den + 1e-16f);
    float2 gb = reinterpret_cast<const float2*>(gat_bias)[lane];
    float2 xr = reinterpret_cast<const float2*>(x + (size_t)wid * 128)[lane];
    float ox = accx * inv + gb.x + xr.x;
    float oy = accy * inv + gb.y + xr.y;
    float sum = ox + oy;
    for (int off = 32; off; off >>= 1) sum += __shfl_xor(sum, off);
    float m = sum * (1.f / 128.f);
    float dx = ox - m, dy = oy - m;
    float sq = dx * dx + dy * dy;
    for (int off = 32; off; off >>= 1) sq += __shfl_xor(sq, off);
    float rstd = rsqrtf(sq * (1.f / 128.f) + LN_EPS);
    float2 g = reinterpret_cast<const float2*>(ln1_g)[lane];
    float2 b = reinterpret_cast<const float2*>(ln1_b)[lane];
    float2 o;
    o.x = dx * rstd * g.x + b.x;
    o.y = dy * rstd * g.y + b.y;
    reinterpret_cast<float2*>(v1 + (size_t)wid * 128)[lane] = o;
}

// ---------------- K_cvt: pre-swizzle W1/W2 into bf16 MFMA B-fragment order ----------------
// B-fragment (16x16x32): lane l supplies B[k][col], col = nt*16 + (l&15),
// k = kk*32 + (l>>4)*8 + j. Linear: W1s[((nt*4+kk)*64 + l)*8 + j], nt=0..31, kk=0..3.
//          W2s[((nt*16+kk)*64 + l)*8 + j], nt=0..7,  kk=0..15.
__global__ __launch_bounds__(256) void k_cvt_w(const float* __restrict__ W1,
                                               const float* __restrict__ W2,
                                               u16* __restrict__ W1s,
                                               u16* __restrict__ W2s) {
    int idx = blockIdx.x * 256 + threadIdx.x;  // 0..131071
    if (idx < 65536) {
        int j = idx & 7, l = (idx >> 3) & 63, kk = (idx >> 9) & 3, nt = idx >> 11;
        int k = kk * 32 + ((l >> 4) << 3) + j, col = nt * 16 + (l & 15);
        W1s[idx] = f2bf(W1[k * 512 + col]);
    } else {
        int i2 = idx - 65536;
        int j = i2 & 7, l = (i2 >> 3) & 63, kk = (i2 >> 9) & 15, nt = i2 >> 13;
        int k = kk * 32 + ((l >> 4) << 3) + j, col = nt * 16 + (l & 15);
        W2s[i2] = f2bf(W2[k * 128 + col]);
    }
}

// ---------------- K6: FFN via bf16 MFMA + residual + LN2, in place on vout ----------------
// 32 rows/block, 256 threads = 4 waves. LDS rows padded so MFMA fragment reads
// (lanes 0..15 = rows, fixed k-slice) spread banks: stride%32words == 4.
#define VTP 132   // vt f32 row stride
#define VAP 136   // va bf16 row stride
#define TTP 520   // tt bf16 row stride
__global__ __launch_bounds__(256) void k_ffn(float* vout,  // aliased v1/out
                                             const u16* __restrict__ W1s,
                                             const float* __restrict__ b1,
                                             const u16* __restrict__ W2s,
                                             const float* __restrict__ b2,
                                             const float* __restrict__ ln2_g,
                                             const float* __restrict__ ln2_b, int n) {
    __shared__ float vt[32 * VTP];  // v1 (residual, then LN2 input)
    __shared__ u16   va[32 * VAP];  // v1 bf16 (phase-1 A operand)
    __shared__ u16   tt[32 * TTP];  // relu'd hidden bf16 (phase-2 A operand)
    int t = threadIdx.x;
    int rowBase = blockIdx.x * 32;
    // stage v1 tile (f32 + bf16 copies); zero-pad invalid rows
    #pragma unroll
    for (int k0 = 0; k0 < 4; ++k0) {
        int idx = t + k0 * 256;
        int r = idx >> 5, c4 = (idx & 31) * 4;
        float4 val = make_float4(0.f, 0.f, 0.f, 0.f);
        if (rowBase + r < n)
            val = *reinterpret_cast<const float4*>(vout + (size_t)(rowBase + r) * 128 + c4);
        *reinterpret_cast<float4*>(&vt[r * VTP + c4]) = val;
        u16* vp = &va[r * VAP + c4];
        vp[0] = f2bf(val.x); vp[1] = f2bf(val.y);
        vp[2] = f2bf(val.z); vp[3] = f2bf(val.w);
    }
    __syncthreads();
    int w = t >> 6, l = t & 63;
    int lr = l & 15;            // fragment row/col index
    int lk = (l >> 4) << 3;     // fragment k-offset
    int qr = (l >> 4) << 2;     // C/D row base

    // ---- phase 1: hidden = relu(va @ W1 + b1); wave w -> cols [w*128, w*128+128)
    f32x4 acc1[2][8];
    #pragma unroll
    for (int m = 0; m < 2; ++m)
        #pragma unroll
        for (int nn = 0; nn < 8; ++nn) acc1[m][nn] = (f32x4){0.f, 0.f, 0.f, 0.f};
    #pragma unroll
    for (int kk = 0; kk < 4; ++kk) {
        bf16x8 a0 = *reinterpret_cast<const bf16x8*>(&va[(lr) * VAP + kk * 32 + lk]);
        bf16x8 a1 = *reinterpret_cast<const bf16x8*>(&va[(16 + lr) * VAP + kk * 32 + lk]);
        #pragma unroll
        for (int nn = 0; nn < 8; ++nn) {
            int nt = w * 8 + nn;
            bf16x8 b = reinterpret_cast<const bf16x8*>(W1s)[(nt * 4 + kk) * 64 + l];
            acc1[0][nn] = __builtin_amdgcn_mfma_f32_16x16x32_bf16(a0, b, acc1[0][nn], 0, 0, 0);
            acc1[1][nn] = __builtin_amdgcn_mfma_f32_16x16x32_bf16(a1, b, acc1[1][nn], 0, 0, 0);
        }
    }
    // epilogue 1: +b1, relu, cvt -> tt  (D map: col=lane&15, row=(lane>>4)*4+r)
    #pragma unroll
    for (int m = 0; m < 2; ++m)
        #pragma unroll
        for (int nn = 0; nn < 8; ++nn) {
            int col = w * 128 + nn * 16 + lr;
            float bias = b1[col];
            #pragma unroll
            for (int r = 0; r < 4; ++r) {
                int row = m * 16 + qr + r;
                float v = acc1[m][nn][r] + bias;
                tt[row * TTP + col] = f2bf(v > 0.f ? v : 0.f);
            }
        }
    __syncthreads();

    // ---- phase 2: out = tt @ W2 + b2 + vt; wave w -> cols [w*32, w*32+32)
    f32x4 acc2[2][2];
    #pragma unroll
    for (int m = 0; m < 2; ++m)
        #pragma unroll
        for (int nn = 0; nn < 2; ++nn) acc2[m][nn] = (f32x4){0.f, 0.f, 0.f, 0.f};
    #pragma unroll 4
    for (int kk = 0; kk < 16; ++kk) {
        bf16x8 a0 = *reinterpret_cast<const bf16x8*>(&tt[(lr) * TTP + kk * 32 + lk]);
        bf16x8 a1 = *reinterpret_cast<const bf16x8*>(&tt[(16 + lr) * TTP + kk * 32 + lk]);
        #pragma unroll
        for (int nn = 0; nn < 2; ++nn) {
            int nt = w * 2 + nn;
            bf16x8 b = reinterpret_cast<const bf16x8*>(W2s)[(nt * 16 + kk) * 64 + l];
            acc2[0][nn] = __builtin_amdgcn_mfma_f32_16x16x32_bf16(a0, b, acc2[0][nn], 0, 0, 0);
            acc2[1][nn] = __builtin_amdgcn_mfma_f32_16x16x32_bf16(a1, b, acc2[1][nn], 0, 0, 0);
        }
    }
    // epilogue 2: +b2 +residual -> vt (f32)
    #pragma unroll
    for (int m = 0; m < 2; ++m)
        #pragma unroll
        for (int nn = 0; nn < 2; ++nn) {
            int col = w * 32 + nn * 16 + lr;
            float bias = b2[col];
            #pragma unroll
            for (int r = 0; r < 4; ++r) {
                int row = m * 16 + qr + r;
                vt[row * VTP + col] = acc2[m][nn][r] + bias + vt[row * VTP + col];
            }
        }
    __syncthreads();
    // LN2: 4 waves x 8 rows = all 32 rows
    float2 g = reinterpret_cast<const float2*>(ln2_g)[l];
    float2 b = reinterpret_cast<const float2*>(ln2_b)[l];
    for (int j = 0; j < 8; ++j) {
        int r = w * 8 + j;
        int grow = rowBase + r;
        float2 val = *reinterpret_cast<const float2*>(&vt[r * VTP + 2 * l]);
        float sum = val.x + val.y;
        for (int off = 32; off; off >>= 1) sum += __shfl_xor(sum, off);
        float m = sum * (1.f / 128.f);
        float dx = val.x - m, dy = val.y - m;
        float sq = dx * dx + dy * dy;
        for (int off = 32; off; off >>= 1) sq += __shfl_xor(sq, off);
        float rstd = rsqrtf(sq * (1.f / 128.f) + LN_EPS);
        float2 o;
        o.x = dx * rstd * g.x + b.x;
        o.y = dy * rstd * g.y + b.y;
        if (grow < n) reinterpret_cast<float2*>(vout + (size_t)grow * 128)[l] = o;
    }
}

// ---------------- host launch ----------------
extern "C" void kernel_launch(void* const* d_in, const int* in_sizes, int n_in,
                              void* d_out, int out_size, void* d_ws, size_t ws_size,
                              hipStream_t stream) {
    const float* x        = (const float*)d_in[0];
    const int*   ei       = (const int*)d_in[1];
    // d_in[2] edge_attr ignored (edge_dim=None in reference)
    const float* W        = (const float*)d_in[3];
    const float* att_src  = (const float*)d_in[4];
    const float* att_dst  = (const float*)d_in[5];
    const float* gat_bias = (const float*)d_in[6];
    const float* W1       = (const float*)d_in[7];
    const float* b1       = (const float*)d_in[8];
    const float* W2       = (const float*)d_in[9];
    const float* b2       = (const float*)d_in[10];
    const float* ln1_g    = (const float*)d_in[11];
    const float* ln1_b    = (const float*)d_in[12];
    const float* ln2_g    = (const float*)d_in[13];
    const float* ln2_b    = (const float*)d_in[14];
    float* out = (float*)d_out;

    const int n = in_sizes[0] / 128;   // 50000
    const int e = in_sizes[1] / 2;     // 800000

    // workspace carve-up (~33 MB)
    char* ws = (char*)d_ws;
    size_t off = 0;
    auto alloc = [&](size_t bytes) -> void* {
        void* p = ws + off;
        off += (bytes + 255) & ~(size_t)255;
        return p;
    };
    float* h         = (float*)alloc((size_t)n * 128 * 4);
    float* a_src     = (float*)alloc((size_t)n * 4);
    float* a_dst     = (float*)alloc((size_t)n * 4);
    int*   deg       = (int*)alloc((size_t)n * 4);        // becomes cursor
    int*   row_start = (int*)alloc((size_t)(n + 1) * 4);
    int*   bsum      = (int*)alloc(256 * 4);
    int*   carry     = (int*)alloc(256 * 4);
    int*   srcs      = (int*)alloc((size_t)(e + n) * 4);
    float* alph      = (float*)alloc((size_t)(e + n) * 4);
    u16*   W1s       = (u16*)alloc(65536 * 2);
    u16*   W2s       = (u16*)alloc(65536 * 2);
    int*   eflag     = (int*)alloc(256);

    const int nchunk = (n + 255) / 256;  // 196 (<=256 required by scan2)

    hipLaunchKernelGGL(k_detect, dim3(1), dim3(256), 0, stream, ei, eflag);
    hipLaunchKernelGGL(k_cvt_w, dim3(512), dim3(256), 0, stream, W1, W2, W1s, W2s);
    hipLaunchKernelGGL(k_gemm_h, dim3(n / 8), dim3(256), 0, stream, x, W, h);
    hipLaunchKernelGGL(k_scores, dim3((n + 3) / 4), dim3(256), 0, stream,
                       h, att_src, att_dst, a_src, a_dst, n);
    hipLaunchKernelGGL(k_init_deg, dim3(nchunk), dim3(256), 0, stream, deg, n);
    hipLaunchKernelGGL(k_count, dim3((e + 255) / 256), dim3(256), 0, stream,
                       ei, eflag, deg, e);
    hipLaunchKernelGGL(k_scan1, dim3(nchunk), dim3(256), 0, stream, deg, row_start, bsum, n);
    hipLaunchKernelGGL(k_scan2, dim3(1), dim3(256), 0, stream, bsum, carry, nchunk);
    hipLaunchKernelGGL(k_scan3, dim3(nchunk), dim3(256), 0, stream,
                       row_start, deg, carry, n, e + n);
    hipLaunchKernelGGL(k_fill, dim3((e + n + 255) / 256), dim3(256), 0, stream,
                       ei, eflag, a_src, a_dst, deg, srcs, alph, e, n);
    hipLaunchKernelGGL(k_aggregate, dim3((n + 3) / 4), dim3(256), 0, stream,
                       h, row_start, srcs, alph, x, gat_bias, ln1_g, ln1_b, out, n);
    hipLaunchKernelGGL(k_ffn, dim3((n + 31) / 32), dim3(256), 0, stream,
                       out, W1s, b1, W2s, b2, ln2_g, ln2_b, n);
}